// Round 9
// baseline (468.649 us; speedup 1.0000x reference)
//
#include <hip/hip_runtime.h>
#include <math.h>

#define QN 900
#define TN 100
#define CN 91
#define PN 1024
#define HWD 128
#define BS 2

__device__ __forceinline__ float sigmoidf_(float x) {
    return 1.0f / (1.0f + __expf(-x));
}
__device__ __forceinline__ float softplusf_(float x) {
    return fmaxf(x, 0.0f) + __logf(1.0f + __expf(-fabsf(x)));
}
__device__ __forceinline__ unsigned bfhi(float f) {   // RNE bf16 in HIGH 16 bits
    unsigned u = __float_as_uint(f);
    return (u + 0x7FFFu + ((u >> 16) & 1u)) & 0xFFFF0000u;
}

// ---------------------------------------------------------------------------
// Prep: 200 blocks: tm bit-pack + popcount sums (nearest sampling).
// ---------------------------------------------------------------------------
__global__ __launch_bounds__(256) void prep_kernel(
    const float2* __restrict__ coords, const int* __restrict__ tmasks,
    unsigned* __restrict__ tmw, float* __restrict__ tmsum)
{
    __shared__ int cnt[4];
    const int bx = blockIdx.x;
    const int tid = threadIdx.x;
    const int wv = tid >> 6, lane = tid & 63;
    const int b = bx / TN, t = bx % TN;
    const int* m = tmasks + (size_t)(b * TN + t) * (HWD * HWD);
    int addr[4]; unsigned vld[4];
#pragma unroll
    for (int c = 0; c < 4; ++c) {
        float2 cd = coords[b * PN + c * 256 + tid];
        int xi = (int)rintf(cd.x * (float)HWD - 0.5f);
        int yi = (int)rintf(cd.y * (float)HWD - 0.5f);
        vld[c] = (xi >= 0) & (xi < HWD) & (yi >= 0) & (yi < HWD);
        addr[c] = min(max(yi, 0), HWD - 1) * HWD + min(max(xi, 0), HWD - 1);
    }
    int rv[4];
#pragma unroll
    for (int c = 0; c < 4; ++c) rv[c] = m[addr[c]];
    int mycnt = 0;
#pragma unroll
    for (int c = 0; c < 4; ++c) {
        unsigned long long bal = __ballot(vld[c] && (rv[c] != 0));
        if (lane == 0) {
            tmw[(size_t)(b * TN + t) * 32 + c * 8 + wv * 2 + 0] = (unsigned)(bal & 0xFFFFFFFFull);
            tmw[(size_t)(b * TN + t) * 32 + c * 8 + wv * 2 + 1] = (unsigned)(bal >> 32);
            mycnt += __popcll(bal);
        }
    }
    if (lane == 0) cnt[wv] = mycnt;
    __syncthreads();
    if (tid == 0)
        tmsum[b * TN + t] = (float)((cnt[0] + cnt[1]) + (cnt[2] + cnt[3]));
}

// ---------------------------------------------------------------------------
// Main: one block (256 thr = 4 waves) per (b,q). WAVE-INDEPENDENT pipeline:
// wave w samples points [w*256, w*256+256) into its own pl slice, then runs
// the bit-masked dual GEMM over that K-slice (targets sliced per lane:
// t0=lane, t1=lane+64). No barrier between sampling and GEMM -> waves hide
// each other's scattered-gather latency. Single combine barrier at the end.
// ---------------------------------------------------------------------------
__global__ __launch_bounds__(256, 4) void main_kernel(
    const float* __restrict__ logits, const float4* __restrict__ pboxes,
    const int* __restrict__ labels, const float4* __restrict__ tboxes,
    const float* __restrict__ pmasks, const float2* __restrict__ coords,
    const unsigned* __restrict__ tmw, const float* __restrict__ tmsum_,
    float* __restrict__ out, float* __restrict__ blockmax)
{
    __shared__ __align__(16) unsigned pl[PN];   // 4 KB packed (bf16 pm | bf16 sg)
    __shared__ float part[TN * 9];              // [t][w*2+s], stride-9 pad
    __shared__ float wred[8];
    __shared__ float mred[256];

    const int bq = blockIdx.x;
    const int b = bq / QN, q = bq - b * QN;
    const int tid = threadIdx.x;
    const int wv = tid >> 6, lane = tid & 63;
    const int P0 = wv * 256;                    // this wave's point slice
    const float* mask = pmasks + (size_t)bq * (HWD * HWD);

    // ---- addresses for this wave's 4 points/lane ----
    int a00[4], a01[4], a10[4], a11[4];
    float wxa[4], wya[4];
    unsigned fl[4];
#pragma unroll
    for (int c = 0; c < 4; ++c) {
        float2 cd = coords[b * PN + P0 + c * 64 + lane];
        float x = cd.x * (float)HWD - 0.5f;
        float y = cd.y * (float)HWD - 0.5f;
        float fx = floorf(x), fy = floorf(y);
        int x0 = (int)fx, y0 = (int)fy;
        int x1 = x0 + 1, y1 = y0 + 1;
        wxa[c] = x - fx; wya[c] = y - fy;
        int xc0 = min(max(x0, 0), HWD - 1), xc1 = min(max(x1, 0), HWD - 1);
        int yc0 = min(max(y0, 0), HWD - 1), yc1 = min(max(y1, 0), HWD - 1);
        a00[c] = yc0 * HWD + xc0; a01[c] = yc0 * HWD + xc1;
        a10[c] = yc1 * HWD + xc0; a11[c] = yc1 * HWD + xc1;
        fl[c] = (unsigned)((x0 >= 0) & (x0 < HWD))
              | ((unsigned)((x1 >= 0) & (x1 < HWD)) << 1)
              | ((unsigned)((y0 >= 0) & (y0 < HWD)) << 2)
              | ((unsigned)((y1 >= 0) & (y1 < HWD)) << 3);
    }

    // ---- issue ALL 16 scattered loads up front ----
    float r00[4], r01[4], r10[4], r11[4];
#pragma unroll
    for (int c = 0; c < 4; ++c) {
        r00[c] = mask[a00[c]];
        r01[c] = mask[a01[c]];
        r10[c] = mask[a10[c]];
        r11[c] = mask[a11[c]];
    }

    // ---- bilinear combine + transcendental -> packed LDS (own slice) ----
    float lsp = 0.f, lsm = 0.f;
#pragma unroll
    for (int c = 0; c < 4; ++c) {
        bool bx0 = fl[c] & 1u, bx1 = fl[c] & 2u, by0 = fl[c] & 4u, by1 = fl[c] & 8u;
        float v00 = (by0 && bx0) ? r00[c] : 0.f;
        float v01 = (by0 && bx1) ? r01[c] : 0.f;
        float v10 = (by1 && bx0) ? r10[c] : 0.f;
        float v11 = (by1 && bx1) ? r11[c] : 0.f;
        float wx = wxa[c], wy = wya[c];
        float pm = (v00 * (1.f - wx) + v01 * wx) * (1.f - wy) +
                   (v10 * (1.f - wx) + v11 * wx) * wy;
        float sg = sigmoidf_(pm);
        lsp += softplusf_(pm);
        lsm += sg;
        pl[P0 + c * 64 + lane] = bfhi(pm) | (bfhi(sg) >> 16);
    }
    for (int off = 32; off > 0; off >>= 1) {
        lsp += __shfl_down(lsp, off);
        lsm += __shfl_down(lsm, off);
    }
    if (lane == 0) { wred[wv * 2 + 0] = lsp; wred[wv * 2 + 1] = lsm; }

    // ---- tmw bit-words for this wave's K-slice (L2-hot) ----
    // point p = wv*256 + g*32 + j  ->  word index t*32 + wv*8 + g, bit j
    const unsigned* rowb = tmw + (size_t)b * TN * 32;
    const int t0 = lane;            // always < 100
    const int t1 = lane + 64;       // valid if lane < 36
    const bool has1 = (t1 < TN);
    unsigned tw0[8], tw1[8];
#pragma unroll
    for (int g = 0; g < 8; ++g) {
        tw0[g] = rowb[t0 * 32 + wv * 8 + g];
        tw1[g] = has1 ? rowb[t1 * 32 + wv * 8 + g] : 0u;
    }

    // ---- wave-local bit-masked dual GEMM over own 256-point slice ----
    // (pl slice written by THIS wave only; lgkmcnt ordering suffices)
    float a0 = 0.f, a1 = 0.f, a2 = 0.f, a3 = 0.f;
#pragma unroll
    for (int g = 0; g < 8; ++g) {
        unsigned u0 = tw0[g], u1 = tw1[g];
        const int base = P0 + g * 32;
#pragma unroll
        for (int jj = 0; jj < 8; ++jj) {
            uint4 u = *(const uint4*)&pl[base + jj * 4];   // wave-uniform addr: broadcast
#pragma unroll
            for (int k = 0; k < 4; ++k) {
                unsigned uv = (k == 0) ? u.x : (k == 1) ? u.y : (k == 2) ? u.z : u.w;
                float pmv = __uint_as_float(uv & 0xFFFF0000u);
                float sgv = __uint_as_float(uv << 16);
                float f0 = (float)(u0 & 1u); u0 >>= 1;
                float f1 = (float)(u1 & 1u); u1 >>= 1;
                a0 = fmaf(pmv, f0, a0); a1 = fmaf(sgv, f0, a1);
                a2 = fmaf(pmv, f1, a2); a3 = fmaf(sgv, f1, a3);
            }
        }
    }
    part[t0 * 9 + wv * 2 + 0] = a0;
    part[t0 * 9 + wv * 2 + 1] = a1;
    if (has1) {
        part[t1 * 9 + wv * 2 + 0] = a2;
        part[t1 * 9 + wv * 2 + 1] = a3;
    }

    // ---- epilogue scalars (L2-hot, issued pre-barrier) ----
    float lg = 0.f, tsum = 0.f;
    float4 tb = make_float4(0, 0, 0, 0), pb = make_float4(0, 0, 0, 0);
    if (tid < TN) {
        int lab = labels[b * TN + tid];
        lg = logits[(size_t)(b * QN + q) * CN + lab];
        tsum = tmsum_[b * TN + tid];
        tb = tboxes[b * TN + tid];
        pb = pboxes[b * QN + q];
    }
    __syncthreads();   // part + wred visible

    float val = -INFINITY;
    if (tid < TN) {
        float s_sp = (wred[0] + wred[2]) + (wred[4] + wred[6]);
        float s_sm = (wred[1] + wred[3]) + (wred[5] + wred[7]);
        float apm = 0.f, asg = 0.f;
#pragma unroll
        for (int w = 0; w < 4; ++w) {
            apm += part[tid * 9 + w * 2 + 0];
            asg += part[tid * 9 + w * 2 + 1];
        }
        float ce = (s_sp - apm) * (1.0f / (float)PN);
        float dice = 1.0f - (2.0f * asg + 1.0f) / (s_sm + tsum + 1.0f);

        float pr = sigmoidf_(lg);
        float cls = 0.25f * (1.f - pr) * (1.f - pr) * softplusf_(-lg)
                  - 0.75f * pr * pr * softplusf_(lg);

        float l1 = fabsf(pb.x - tb.x) + fabsf(pb.y - tb.y) +
                   fabsf(pb.z - tb.z) + fabsf(pb.w - tb.w);

        float px1 = pb.x - 0.5f * pb.z, py1 = pb.y - 0.5f * pb.w;
        float px2 = pb.x + 0.5f * pb.z, py2 = pb.y + 0.5f * pb.w;
        float tx1 = tb.x - 0.5f * tb.z, ty1 = tb.y - 0.5f * tb.w;
        float tx2 = tb.x + 0.5f * tb.z, ty2 = tb.y + 0.5f * tb.w;
        float A1 = (px2 - px1) * (py2 - py1);
        float A2 = (tx2 - tx1) * (ty2 - ty1);
        float iw = fmaxf(fminf(px2, tx2) - fmaxf(px1, tx1), 0.f);
        float ih = fmaxf(fminf(py2, ty2) - fmaxf(py1, ty1), 0.f);
        float inter = iw * ih;
        float uni = A1 + A2 - inter;
        float iou = inter / uni;
        float cw = fmaxf(fmaxf(px2, tx2) - fminf(px1, tx1), 0.f);
        float chh = fmaxf(fmaxf(py2, ty2) - fminf(py1, ty1), 0.f);
        float area = cw * chh;
        float giou = iou - (area - uni) / area;

        float Cv = l1 + cls - giou + ce + dice;
        out[(size_t)(b * QN + q) * TN + tid] = Cv;
        if (isfinite(Cv)) val = Cv;
    }
    mred[tid] = val;
    __syncthreads();
    if (tid < 64) {
        float m = fmaxf(fmaxf(mred[tid], mred[tid + 64]),
                        fmaxf(mred[tid + 128], mred[tid + 192]));
        for (int off = 32; off > 0; off >>= 1)
            m = fmaxf(m, __shfl_down(m, off));
        if (tid == 0) blockmax[bq] = m;
    }
}

// ---------------------------------------------------------------------------
// Fixup: C = where(finite, C, 2*max_finite) per batch. Fast path: no-op.
// ---------------------------------------------------------------------------
__global__ __launch_bounds__(256) void fix_kernel(float* __restrict__ out,
                                                  const float* __restrict__ blockmax)
{
    __shared__ int bad;
    int tid = threadIdx.x;
    int i = blockIdx.x * 256 + tid;
    bool active = (i < BS * QN * TN);
    float v = active ? out[i] : 0.0f;
    if (tid == 0) bad = 0;
    __syncthreads();
    if (!isfinite(v)) bad = 1;   // benign same-value race
    __syncthreads();
    if (!bad) return;            // uniform across block
    if (!isfinite(v)) {
        int b = i / (QN * TN);
        float m = -INFINITY;
        for (int k = 0; k < QN; ++k) m = fmaxf(m, blockmax[b * QN + k]);
        out[i] = 2.0f * m;
    }
}

extern "C" void kernel_launch(void* const* d_in, const int* in_sizes, int n_in,
                              void* d_out, int out_size, void* d_ws, size_t ws_size,
                              hipStream_t stream) {
    const float* logits  = (const float*)d_in[0];
    const float4* pboxes = (const float4*)d_in[1];
    const int* labels    = (const int*)d_in[2];
    const float4* tboxes = (const float4*)d_in[3];
    const float* pmasks  = (const float*)d_in[4];
    const int* tmasks    = (const int*)d_in[5];
    const float* coords  = (const float*)d_in[6];
    float* out = (float*)d_out;

    char* ws = (char*)d_ws;
    unsigned* tmw   = (unsigned*)(ws);            // 25600 B
    float* tmsum    = (float*)(ws + 25600);       // 800 B
    float* blockmax = (float*)(ws + 26400);       // 7200 B

    hipLaunchKernelGGL(prep_kernel, dim3(BS * TN), dim3(256), 0, stream,
                       (const float2*)coords, tmasks, tmw, tmsum);
    hipLaunchKernelGGL(main_kernel, dim3(BS * QN), dim3(256), 0, stream,
                       logits, pboxes, labels, tboxes, pmasks, (const float2*)coords,
                       tmw, tmsum, out, blockmax);
    hipLaunchKernelGGL(fix_kernel, dim3((BS * QN * TN + 255) / 256), dim3(256), 0, stream,
                       out, blockmax);
}

// Round 10
// 60.985 us; speedup vs baseline: 7.6847x; 7.6847x over previous
//
#include <hip/hip_runtime.h>
#include <math.h>

#define QN 900
#define TN 100
#define CN 91
#define PN 1024
#define HWD 128
#define BS 2

__device__ __forceinline__ float sigmoidf_(float x) {
    return 1.0f / (1.0f + __expf(-x));
}
__device__ __forceinline__ float softplusf_(float x) {
    return fmaxf(x, 0.0f) + __logf(1.0f + __expf(-fabsf(x)));
}
__device__ __forceinline__ unsigned bfhi(float f) {   // RNE bf16 in HIGH 16 bits
    unsigned u = __float_as_uint(f);
    return (u + 0x7FFFu + ((u >> 16) & 1u)) & 0xFFFF0000u;
}

// ---------------------------------------------------------------------------
// Prep: 200 blocks: tm bit-pack + popcount sums (nearest sampling).
// ---------------------------------------------------------------------------
__global__ __launch_bounds__(256) void prep_kernel(
    const float2* __restrict__ coords, const int* __restrict__ tmasks,
    unsigned* __restrict__ tmw, float* __restrict__ tmsum)
{
    __shared__ int cnt[4];
    const int bx = blockIdx.x;
    const int tid = threadIdx.x;
    const int wv = tid >> 6, lane = tid & 63;
    const int b = bx / TN, t = bx % TN;
    const int* m = tmasks + (size_t)(b * TN + t) * (HWD * HWD);
    // addresses first, loads batched
    int addr[4]; unsigned vld[4];
#pragma unroll
    for (int c = 0; c < 4; ++c) {
        float2 cd = coords[b * PN + c * 256 + tid];
        int xi = (int)rintf(cd.x * (float)HWD - 0.5f);
        int yi = (int)rintf(cd.y * (float)HWD - 0.5f);
        vld[c] = (xi >= 0) & (xi < HWD) & (yi >= 0) & (yi < HWD);
        addr[c] = min(max(yi, 0), HWD - 1) * HWD + min(max(xi, 0), HWD - 1);
    }
    int rv[4];
#pragma unroll
    for (int c = 0; c < 4; ++c) rv[c] = m[addr[c]];
    int mycnt = 0;
#pragma unroll
    for (int c = 0; c < 4; ++c) {
        unsigned long long bal = __ballot(vld[c] && (rv[c] != 0));
        if (lane == 0) {
            tmw[(size_t)(b * TN + t) * 32 + c * 8 + wv * 2 + 0] = (unsigned)(bal & 0xFFFFFFFFull);
            tmw[(size_t)(b * TN + t) * 32 + c * 8 + wv * 2 + 1] = (unsigned)(bal >> 32);
            mycnt += __popcll(bal);
        }
    }
    if (lane == 0) cnt[wv] = mycnt;
    __syncthreads();
    if (tid == 0)
        tmsum[b * TN + t] = (float)((cnt[0] + cnt[1]) + (cnt[2] + cnt[3]));
}

// ---------------------------------------------------------------------------
// Main: one block (256 thr) per (b,q). Batched scattered sampling from global
// (16 loads in flight before first use), pm/sg packed bf16 -> 4KB LDS,
// bit-masked dual GEMM vs 100 targets, fused epilogue.
// launch_bounds(256,6): VGPR cap ~85 >= the 48 this kernel needs (round 7),
// so codegen is unchanged vs round 7 while the scheduler gets residency
// headroom. (256,8) spilled (VGPR 32, +56MB scratch) - round 8 falsifier.
// ---------------------------------------------------------------------------
__global__ __launch_bounds__(256, 6) void main_kernel(
    const float* __restrict__ logits, const float4* __restrict__ pboxes,
    const int* __restrict__ labels, const float4* __restrict__ tboxes,
    const float* __restrict__ pmasks, const float2* __restrict__ coords,
    const unsigned* __restrict__ tmw, const float* __restrict__ tmsum_,
    float* __restrict__ out, float* __restrict__ blockmax)
{
    __shared__ unsigned pl[PN];            // 4 KB packed (bf16 pm | bf16 sg)
    __shared__ float part[8][32][9];       // 9.2 KB (stride-9: conflict-free)
    __shared__ float sred[8];
    __shared__ float mred[256];

    const int bq = blockIdx.x;
    const int b = bq / QN, q = bq - b * QN;
    const int tid = threadIdx.x;
    const int wv = tid >> 6, lane = tid & 63;
    const int pc = tid >> 5, ts = tid & 31;
    const float* mask = pmasks + (size_t)bq * (HWD * HWD);

    // ---- addresses for 4 points/thread ----
    int a00[4], a01[4], a10[4], a11[4];
    float wxa[4], wya[4];
    unsigned fl[4];
#pragma unroll
    for (int c = 0; c < 4; ++c) {
        float2 cd = coords[b * PN + c * 256 + tid];
        float x = cd.x * (float)HWD - 0.5f;
        float y = cd.y * (float)HWD - 0.5f;
        float fx = floorf(x), fy = floorf(y);
        int x0 = (int)fx, y0 = (int)fy;
        int x1 = x0 + 1, y1 = y0 + 1;
        wxa[c] = x - fx; wya[c] = y - fy;
        int xc0 = min(max(x0, 0), HWD - 1), xc1 = min(max(x1, 0), HWD - 1);
        int yc0 = min(max(y0, 0), HWD - 1), yc1 = min(max(y1, 0), HWD - 1);
        a00[c] = yc0 * HWD + xc0; a01[c] = yc0 * HWD + xc1;
        a10[c] = yc1 * HWD + xc0; a11[c] = yc1 * HWD + xc1;
        fl[c] = (unsigned)((x0 >= 0) & (x0 < HWD))
              | ((unsigned)((x1 >= 0) & (x1 < HWD)) << 1)
              | ((unsigned)((y0 >= 0) & (y0 < HWD)) << 2)
              | ((unsigned)((y1 >= 0) & (y1 < HWD)) << 3);
    }

    // ---- issue ALL 16 scattered loads up front ----
    float r00[4], r01[4], r10[4], r11[4];
#pragma unroll
    for (int c = 0; c < 4; ++c) {
        r00[c] = mask[a00[c]];
        r01[c] = mask[a01[c]];
        r10[c] = mask[a10[c]];
        r11[c] = mask[a11[c]];
    }

    // ---- under the shadow: tmw words + epilogue scalars ----
    const unsigned* rowb = tmw + (size_t)b * TN * 32;
    unsigned w0[4], w1[4], w2[4], w3[4];
#pragma unroll
    for (int g = 0; g < 4; ++g) {
        w0[g] = rowb[(ts +  0) * 32 + pc * 4 + g];
        w1[g] = rowb[(ts + 32) * 32 + pc * 4 + g];
        w2[g] = rowb[(ts + 64) * 32 + pc * 4 + g];
        w3[g] = (ts + 96 < TN) ? rowb[(ts + 96) * 32 + pc * 4 + g] : 0u;
    }
    float lg = 0.f, tsum = 0.f;
    float4 tb = make_float4(0, 0, 0, 0), pb = make_float4(0, 0, 0, 0);
    if (tid < TN) {
        int lab = labels[b * TN + tid];
        lg = logits[(size_t)(b * QN + q) * CN + lab];
        tsum = tmsum_[b * TN + tid];
        tb = tboxes[b * TN + tid];
        pb = pboxes[b * QN + q];
    }

    // ---- bilinear combine + pointwise transcendental -> packed LDS ----
    float lsp = 0.f, lsm = 0.f;
#pragma unroll
    for (int c = 0; c < 4; ++c) {
        bool bx0 = fl[c] & 1u, bx1 = fl[c] & 2u, by0 = fl[c] & 4u, by1 = fl[c] & 8u;
        float v00 = (by0 && bx0) ? r00[c] : 0.f;
        float v01 = (by0 && bx1) ? r01[c] : 0.f;
        float v10 = (by1 && bx0) ? r10[c] : 0.f;
        float v11 = (by1 && bx1) ? r11[c] : 0.f;
        float wx = wxa[c], wy = wya[c];
        float pm = (v00 * (1.f - wx) + v01 * wx) * (1.f - wy) +
                   (v10 * (1.f - wx) + v11 * wx) * wy;
        float sg = sigmoidf_(pm);
        lsp += softplusf_(pm);
        lsm += sg;
        pl[c * 256 + tid] = bfhi(pm) | (bfhi(sg) >> 16);
    }
    for (int off = 32; off > 0; off >>= 1) {
        lsp += __shfl_down(lsp, off);
        lsm += __shfl_down(lsm, off);
    }
    if (lane == 0) { sred[wv * 2 + 0] = lsp; sred[wv * 2 + 1] = lsm; }
    __syncthreads();
    float s_sp = (sred[0] + sred[2]) + (sred[4] + sred[6]);
    float s_sm = (sred[1] + sred[3]) + (sred[5] + sred[7]);

    // ---- bit-masked dual GEMM: chunk pc (128 points) x 4 targets ----
    float a0 = 0, a1 = 0, a2 = 0, a3 = 0, a4 = 0, a5 = 0, a6 = 0, a7 = 0;
#pragma unroll
    for (int g = 0; g < 4; ++g) {
        unsigned u0 = w0[g], u1 = w1[g], u2 = w2[g], u3 = w3[g];
        int p0 = pc * 128 + g * 32;
#pragma unroll
        for (int jj = 0; jj < 8; ++jj) {
            uint4 u = *(const uint4*)&pl[p0 + jj * 4];   // broadcast within half-wave
#pragma unroll
            for (int k = 0; k < 4; ++k) {
                unsigned uv = (k == 0) ? u.x : (k == 1) ? u.y : (k == 2) ? u.z : u.w;
                float pmv = __uint_as_float(uv & 0xFFFF0000u);
                float sgv = __uint_as_float(uv << 16);
                float f0 = (float)((u0 >> k) & 1u);
                float f1 = (float)((u1 >> k) & 1u);
                float f2 = (float)((u2 >> k) & 1u);
                float f3 = (float)((u3 >> k) & 1u);
                a0 = fmaf(pmv, f0, a0); a1 = fmaf(sgv, f0, a1);
                a2 = fmaf(pmv, f1, a2); a3 = fmaf(sgv, f1, a3);
                a4 = fmaf(pmv, f2, a4); a5 = fmaf(sgv, f2, a5);
                a6 = fmaf(pmv, f3, a6); a7 = fmaf(sgv, f3, a7);
            }
            u0 >>= 4; u1 >>= 4; u2 >>= 4; u3 >>= 4;
        }
    }
    part[pc][ts][0] = a0; part[pc][ts][1] = a1;
    part[pc][ts][2] = a2; part[pc][ts][3] = a3;
    part[pc][ts][4] = a4; part[pc][ts][5] = a5;
    part[pc][ts][6] = a6; part[pc][ts][7] = a7;
    __syncthreads();

    // ---- epilogue ----
    float val = -INFINITY;
    if (tid < TN) {
        int t = tid, tss = t & 31, kk = t >> 5;
        float apm = 0.f, asg = 0.f;
#pragma unroll
        for (int pp = 0; pp < 8; ++pp) {
            apm += part[pp][tss][kk * 2 + 0];
            asg += part[pp][tss][kk * 2 + 1];
        }
        float ce = (s_sp - apm) * (1.0f / (float)PN);
        float dice = 1.0f - (2.0f * asg + 1.0f) / (s_sm + tsum + 1.0f);

        float pr = sigmoidf_(lg);
        float cls = 0.25f * (1.f - pr) * (1.f - pr) * softplusf_(-lg)
                  - 0.75f * pr * pr * softplusf_(lg);

        float l1 = fabsf(pb.x - tb.x) + fabsf(pb.y - tb.y) +
                   fabsf(pb.z - tb.z) + fabsf(pb.w - tb.w);

        float px1 = pb.x - 0.5f * pb.z, py1 = pb.y - 0.5f * pb.w;
        float px2 = pb.x + 0.5f * pb.z, py2 = pb.y + 0.5f * pb.w;
        float tx1 = tb.x - 0.5f * tb.z, ty1 = tb.y - 0.5f * tb.w;
        float tx2 = tb.x + 0.5f * tb.z, ty2 = tb.y + 0.5f * tb.w;
        float A1 = (px2 - px1) * (py2 - py1);
        float A2 = (tx2 - tx1) * (ty2 - ty1);
        float iw = fmaxf(fminf(px2, tx2) - fmaxf(px1, tx1), 0.f);
        float ih = fmaxf(fminf(py2, ty2) - fmaxf(py1, ty1), 0.f);
        float inter = iw * ih;
        float uni = A1 + A2 - inter;
        float iou = inter / uni;
        float cw = fmaxf(fmaxf(px2, tx2) - fminf(px1, tx1), 0.f);
        float chh = fmaxf(fmaxf(py2, ty2) - fminf(py1, ty1), 0.f);
        float area = cw * chh;
        float giou = iou - (area - uni) / area;

        float Cv = l1 + cls - giou + ce + dice;
        out[(size_t)(b * QN + q) * TN + t] = Cv;
        if (isfinite(Cv)) val = Cv;
    }
    mred[tid] = val;
    __syncthreads();
    if (tid < 64) {
        float m = fmaxf(fmaxf(mred[tid], mred[tid + 64]),
                        fmaxf(mred[tid + 128], mred[tid + 192]));
        for (int off = 32; off > 0; off >>= 1)
            m = fmaxf(m, __shfl_down(m, off));
        if (tid == 0) blockmax[bq] = m;
    }
}

// ---------------------------------------------------------------------------
// Fixup: C = where(finite, C, 2*max_finite) per batch. Fast path: no-op.
// ---------------------------------------------------------------------------
__global__ __launch_bounds__(256) void fix_kernel(float* __restrict__ out,
                                                  const float* __restrict__ blockmax)
{
    __shared__ int bad;
    int tid = threadIdx.x;
    int i = blockIdx.x * 256 + tid;
    bool active = (i < BS * QN * TN);
    float v = active ? out[i] : 0.0f;
    if (tid == 0) bad = 0;
    __syncthreads();
    if (!isfinite(v)) bad = 1;   // benign same-value race
    __syncthreads();
    if (!bad) return;            // uniform across block
    if (!isfinite(v)) {
        int b = i / (QN * TN);
        float m = -INFINITY;
        for (int k = 0; k < QN; ++k) m = fmaxf(m, blockmax[b * QN + k]);
        out[i] = 2.0f * m;
    }
}

extern "C" void kernel_launch(void* const* d_in, const int* in_sizes, int n_in,
                              void* d_out, int out_size, void* d_ws, size_t ws_size,
                              hipStream_t stream) {
    const float* logits  = (const float*)d_in[0];
    const float4* pboxes = (const float4*)d_in[1];
    const int* labels    = (const int*)d_in[2];
    const float4* tboxes = (const float4*)d_in[3];
    const float* pmasks  = (const float*)d_in[4];
    const int* tmasks    = (const int*)d_in[5];
    const float* coords  = (const float*)d_in[6];
    float* out = (float*)d_out;

    char* ws = (char*)d_ws;
    unsigned* tmw   = (unsigned*)(ws);            // 25600 B
    float* tmsum    = (float*)(ws + 25600);       // 800 B
    float* blockmax = (float*)(ws + 26400);       // 7200 B

    hipLaunchKernelGGL(prep_kernel, dim3(BS * TN), dim3(256), 0, stream,
                       (const float2*)coords, tmasks, tmw, tmsum);
    hipLaunchKernelGGL(main_kernel, dim3(BS * QN), dim3(256), 0, stream,
                       logits, pboxes, labels, tboxes, pmasks, (const float2*)coords,
                       tmw, tmsum, out, blockmax);
    hipLaunchKernelGGL(fix_kernel, dim3((BS * QN * TN + 255) / 256), dim3(256), 0, stream,
                       out, blockmax);
}

// Round 11
// 54.946 us; speedup vs baseline: 8.5293x; 1.1099x over previous
//
#include <hip/hip_runtime.h>
#include <math.h>

#define QN 900
#define TN 100
#define CN 91
#define PN 1024
#define HWD 128
#define BS 2

__device__ __forceinline__ float sigmoidf_(float x) {
    return 1.0f / (1.0f + __expf(-x));
}
__device__ __forceinline__ float softplusf_(float x) {
    return fmaxf(x, 0.0f) + __logf(1.0f + __expf(-fabsf(x)));
}
__device__ __forceinline__ unsigned bfhi(float f) {   // RNE bf16 in HIGH 16 bits
    unsigned u = __float_as_uint(f);
    return (u + 0x7FFFu + ((u >> 16) & 1u)) & 0xFFFF0000u;
}

// ---------------------------------------------------------------------------
// Prep: 200 blocks: tm bit-pack + popcount sums (nearest sampling).
// ---------------------------------------------------------------------------
__global__ __launch_bounds__(256) void prep_kernel(
    const float2* __restrict__ coords, const int* __restrict__ tmasks,
    unsigned* __restrict__ tmw, float* __restrict__ tmsum)
{
    __shared__ int cnt[4];
    const int bx = blockIdx.x;
    const int tid = threadIdx.x;
    const int wv = tid >> 6, lane = tid & 63;
    const int b = bx / TN, t = bx % TN;
    const int* m = tmasks + (size_t)(b * TN + t) * (HWD * HWD);
    int addr[4]; unsigned vld[4];
#pragma unroll
    for (int c = 0; c < 4; ++c) {
        float2 cd = coords[b * PN + c * 256 + tid];
        int xi = (int)rintf(cd.x * (float)HWD - 0.5f);
        int yi = (int)rintf(cd.y * (float)HWD - 0.5f);
        vld[c] = (xi >= 0) & (xi < HWD) & (yi >= 0) & (yi < HWD);
        addr[c] = min(max(yi, 0), HWD - 1) * HWD + min(max(xi, 0), HWD - 1);
    }
    int rv[4];
#pragma unroll
    for (int c = 0; c < 4; ++c) rv[c] = m[addr[c]];
    int mycnt = 0;
#pragma unroll
    for (int c = 0; c < 4; ++c) {
        unsigned long long bal = __ballot(vld[c] && (rv[c] != 0));
        if (lane == 0) {
            tmw[(size_t)(b * TN + t) * 32 + c * 8 + wv * 2 + 0] = (unsigned)(bal & 0xFFFFFFFFull);
            tmw[(size_t)(b * TN + t) * 32 + c * 8 + wv * 2 + 1] = (unsigned)(bal >> 32);
            mycnt += __popcll(bal);
        }
    }
    if (lane == 0) cnt[wv] = mycnt;
    __syncthreads();
    if (tid == 0)
        tmsum[b * TN + t] = (float)((cnt[0] + cnt[1]) + (cnt[2] + cnt[3]));
}

// ---------------------------------------------------------------------------
// Main: one block (256 thr) per (b,q). Round-7 structure (the stable VGPR-48
// config; launch_bounds MUST stay (256,4) — 6/8 both spill). Changes vs r7:
// (a) bit-GEMM uint4 stream is explicitly software-prefetched 2-deep to
// cover ds_read_b128 latency; (b) per-row badflag so fix_kernel can
// early-exit without re-reading the output.
// ---------------------------------------------------------------------------
__global__ __launch_bounds__(256, 4) void main_kernel(
    const float* __restrict__ logits, const float4* __restrict__ pboxes,
    const int* __restrict__ labels, const float4* __restrict__ tboxes,
    const float* __restrict__ pmasks, const float2* __restrict__ coords,
    const unsigned* __restrict__ tmw, const float* __restrict__ tmsum_,
    float* __restrict__ out, float* __restrict__ blockmax,
    int* __restrict__ badflag)
{
    __shared__ unsigned pl[PN];            // 4 KB packed (bf16 pm | bf16 sg)
    __shared__ float part[8][32][9];       // 9.2 KB (stride-9: conflict-free)
    __shared__ float sred[8];
    __shared__ float mred[256];
    __shared__ int sbad;

    const int bq = blockIdx.x;
    const int b = bq / QN, q = bq - b * QN;
    const int tid = threadIdx.x;
    const int wv = tid >> 6, lane = tid & 63;
    const int pc = tid >> 5, ts = tid & 31;
    const float* mask = pmasks + (size_t)bq * (HWD * HWD);

    if (tid == 0) sbad = 0;

    // ---- addresses for 4 points/thread ----
    int a00[4], a01[4], a10[4], a11[4];
    float wxa[4], wya[4];
    unsigned fl[4];
#pragma unroll
    for (int c = 0; c < 4; ++c) {
        float2 cd = coords[b * PN + c * 256 + tid];
        float x = cd.x * (float)HWD - 0.5f;
        float y = cd.y * (float)HWD - 0.5f;
        float fx = floorf(x), fy = floorf(y);
        int x0 = (int)fx, y0 = (int)fy;
        int x1 = x0 + 1, y1 = y0 + 1;
        wxa[c] = x - fx; wya[c] = y - fy;
        int xc0 = min(max(x0, 0), HWD - 1), xc1 = min(max(x1, 0), HWD - 1);
        int yc0 = min(max(y0, 0), HWD - 1), yc1 = min(max(y1, 0), HWD - 1);
        a00[c] = yc0 * HWD + xc0; a01[c] = yc0 * HWD + xc1;
        a10[c] = yc1 * HWD + xc0; a11[c] = yc1 * HWD + xc1;
        fl[c] = (unsigned)((x0 >= 0) & (x0 < HWD))
              | ((unsigned)((x1 >= 0) & (x1 < HWD)) << 1)
              | ((unsigned)((y0 >= 0) & (y0 < HWD)) << 2)
              | ((unsigned)((y1 >= 0) & (y1 < HWD)) << 3);
    }

    // ---- issue ALL 16 scattered loads up front ----
    float r00[4], r01[4], r10[4], r11[4];
#pragma unroll
    for (int c = 0; c < 4; ++c) {
        r00[c] = mask[a00[c]];
        r01[c] = mask[a01[c]];
        r10[c] = mask[a10[c]];
        r11[c] = mask[a11[c]];
    }

    // ---- under the shadow: tmw words + epilogue scalars ----
    const unsigned* rowb = tmw + (size_t)b * TN * 32;
    unsigned w0[4], w1[4], w2[4], w3[4];
#pragma unroll
    for (int g = 0; g < 4; ++g) {
        w0[g] = rowb[(ts +  0) * 32 + pc * 4 + g];
        w1[g] = rowb[(ts + 32) * 32 + pc * 4 + g];
        w2[g] = rowb[(ts + 64) * 32 + pc * 4 + g];
        w3[g] = (ts + 96 < TN) ? rowb[(ts + 96) * 32 + pc * 4 + g] : 0u;
    }
    float lg = 0.f, tsum = 0.f;
    float4 tb = make_float4(0, 0, 0, 0), pb = make_float4(0, 0, 0, 0);
    if (tid < TN) {
        int lab = labels[b * TN + tid];
        lg = logits[(size_t)(b * QN + q) * CN + lab];
        tsum = tmsum_[b * TN + tid];
        tb = tboxes[b * TN + tid];
        pb = pboxes[b * QN + q];
    }

    // ---- bilinear combine + pointwise transcendental -> packed LDS ----
    float lsp = 0.f, lsm = 0.f;
#pragma unroll
    for (int c = 0; c < 4; ++c) {
        bool bx0 = fl[c] & 1u, bx1 = fl[c] & 2u, by0 = fl[c] & 4u, by1 = fl[c] & 8u;
        float v00 = (by0 && bx0) ? r00[c] : 0.f;
        float v01 = (by0 && bx1) ? r01[c] : 0.f;
        float v10 = (by1 && bx0) ? r10[c] : 0.f;
        float v11 = (by1 && bx1) ? r11[c] : 0.f;
        float wx = wxa[c], wy = wya[c];
        float pm = (v00 * (1.f - wx) + v01 * wx) * (1.f - wy) +
                   (v10 * (1.f - wx) + v11 * wx) * wy;
        float sg = sigmoidf_(pm);
        lsp += softplusf_(pm);
        lsm += sg;
        pl[c * 256 + tid] = bfhi(pm) | (bfhi(sg) >> 16);
    }
    for (int off = 32; off > 0; off >>= 1) {
        lsp += __shfl_down(lsp, off);
        lsm += __shfl_down(lsm, off);
    }
    if (lane == 0) { sred[wv * 2 + 0] = lsp; sred[wv * 2 + 1] = lsm; }
    __syncthreads();
    float s_sp = (sred[0] + sred[2]) + (sred[4] + sred[6]);
    float s_sm = (sred[1] + sred[3]) + (sred[5] + sred[7]);

    // ---- bit-masked dual GEMM, 2-deep prefetched uint4 stream ----
    // flattened it = g*8 + jj; uint4 index = pc*128/4 + it; bits (jj*4+k).
    float a0 = 0, a1 = 0, a2 = 0, a3 = 0, a4 = 0, a5 = 0, a6 = 0, a7 = 0;
    {
        const uint4* plv = (const uint4*)&pl[pc * 128];
        uint4 ua = plv[0];
        uint4 ub = plv[1];
#pragma unroll
        for (int it = 0; it < 32; ++it) {
            const int g = it >> 3, sh = (it & 7) * 4;
            uint4 ucur = ua;
            ua = ub;
            if (it < 30) ub = plv[it + 2];
            unsigned q0 = w0[g] >> sh;
            unsigned q1 = w1[g] >> sh;
            unsigned q2 = w2[g] >> sh;
            unsigned q3 = w3[g] >> sh;
#pragma unroll
            for (int k = 0; k < 4; ++k) {
                unsigned uv = (k == 0) ? ucur.x : (k == 1) ? ucur.y : (k == 2) ? ucur.z : ucur.w;
                float pmv = __uint_as_float(uv & 0xFFFF0000u);
                float sgv = __uint_as_float(uv << 16);
                float f0 = (float)((q0 >> k) & 1u);
                float f1 = (float)((q1 >> k) & 1u);
                float f2 = (float)((q2 >> k) & 1u);
                float f3 = (float)((q3 >> k) & 1u);
                a0 = fmaf(pmv, f0, a0); a1 = fmaf(sgv, f0, a1);
                a2 = fmaf(pmv, f1, a2); a3 = fmaf(sgv, f1, a3);
                a4 = fmaf(pmv, f2, a4); a5 = fmaf(sgv, f2, a5);
                a6 = fmaf(pmv, f3, a6); a7 = fmaf(sgv, f3, a7);
            }
        }
    }
    part[pc][ts][0] = a0; part[pc][ts][1] = a1;
    part[pc][ts][2] = a2; part[pc][ts][3] = a3;
    part[pc][ts][4] = a4; part[pc][ts][5] = a5;
    part[pc][ts][6] = a6; part[pc][ts][7] = a7;
    __syncthreads();

    // ---- epilogue ----
    float val = -INFINITY;
    if (tid < TN) {
        int t = tid, tss = t & 31, kk = t >> 5;
        float apm = 0.f, asg = 0.f;
#pragma unroll
        for (int pp = 0; pp < 8; ++pp) {
            apm += part[pp][tss][kk * 2 + 0];
            asg += part[pp][tss][kk * 2 + 1];
        }
        float ce = (s_sp - apm) * (1.0f / (float)PN);
        float dice = 1.0f - (2.0f * asg + 1.0f) / (s_sm + tsum + 1.0f);

        float pr = sigmoidf_(lg);
        float cls = 0.25f * (1.f - pr) * (1.f - pr) * softplusf_(-lg)
                  - 0.75f * pr * pr * softplusf_(lg);

        float l1 = fabsf(pb.x - tb.x) + fabsf(pb.y - tb.y) +
                   fabsf(pb.z - tb.z) + fabsf(pb.w - tb.w);

        float px1 = pb.x - 0.5f * pb.z, py1 = pb.y - 0.5f * pb.w;
        float px2 = pb.x + 0.5f * pb.z, py2 = pb.y + 0.5f * pb.w;
        float tx1 = tb.x - 0.5f * tb.z, ty1 = tb.y - 0.5f * tb.w;
        float tx2 = tb.x + 0.5f * tb.z, ty2 = tb.y + 0.5f * tb.w;
        float A1 = (px2 - px1) * (py2 - py1);
        float A2 = (tx2 - tx1) * (ty2 - ty1);
        float iw = fmaxf(fminf(px2, tx2) - fmaxf(px1, tx1), 0.f);
        float ih = fmaxf(fminf(py2, ty2) - fmaxf(py1, ty1), 0.f);
        float inter = iw * ih;
        float uni = A1 + A2 - inter;
        float iou = inter / uni;
        float cw = fmaxf(fmaxf(px2, tx2) - fminf(px1, tx1), 0.f);
        float chh = fmaxf(fmaxf(py2, ty2) - fminf(py1, ty1), 0.f);
        float area = cw * chh;
        float giou = iou - (area - uni) / area;

        float Cv = l1 + cls - giou + ce + dice;
        out[(size_t)(b * QN + q) * TN + t] = Cv;
        if (isfinite(Cv)) val = Cv;
        else sbad = 1;             // benign same-value race
    }
    mred[tid] = val;
    __syncthreads();
    if (tid < 64) {
        float m = fmaxf(fmaxf(mred[tid], mred[tid + 64]),
                        fmaxf(mred[tid + 128], mred[tid + 192]));
        for (int off = 32; off > 0; off >>= 1)
            m = fmaxf(m, __shfl_down(m, off));
        if (tid == 0) { blockmax[bq] = m; badflag[bq] = sbad; }
    }
}

// ---------------------------------------------------------------------------
// Fixup: C = where(finite, C, 2*max_finite) per batch. Gated by per-row
// badflag: the common all-finite case costs one scalar load per block.
// ---------------------------------------------------------------------------
__global__ __launch_bounds__(128) void fix_kernel(float* __restrict__ out,
                                                  const float* __restrict__ blockmax,
                                                  const int* __restrict__ badflag)
{
    const int bq = blockIdx.x;
    if (badflag[bq] == 0) return;       // uniform early exit
    const int tid = threadIdx.x;
    if (tid >= TN) return;
    const int b = bq / QN;
    float v = out[(size_t)bq * TN + tid];
    if (!isfinite(v)) {
        float m = -INFINITY;
        for (int k = 0; k < QN; ++k) m = fmaxf(m, blockmax[b * QN + k]);
        out[(size_t)bq * TN + tid] = 2.0f * m;
    }
}

extern "C" void kernel_launch(void* const* d_in, const int* in_sizes, int n_in,
                              void* d_out, int out_size, void* d_ws, size_t ws_size,
                              hipStream_t stream) {
    const float* logits  = (const float*)d_in[0];
    const float4* pboxes = (const float4*)d_in[1];
    const int* labels    = (const int*)d_in[2];
    const float4* tboxes = (const float4*)d_in[3];
    const float* pmasks  = (const float*)d_in[4];
    const int* tmasks    = (const int*)d_in[5];
    const float* coords  = (const float*)d_in[6];
    float* out = (float*)d_out;

    char* ws = (char*)d_ws;
    unsigned* tmw   = (unsigned*)(ws);            // 25600 B
    float* tmsum    = (float*)(ws + 25600);       // 800 B
    float* blockmax = (float*)(ws + 26400);       // 7200 B
    int* badflag    = (int*)(ws + 33600);         // 7200 B

    hipLaunchKernelGGL(prep_kernel, dim3(BS * TN), dim3(256), 0, stream,
                       (const float2*)coords, tmasks, tmw, tmsum);
    hipLaunchKernelGGL(main_kernel, dim3(BS * QN), dim3(256), 0, stream,
                       logits, pboxes, labels, tboxes, pmasks, (const float2*)coords,
                       tmw, tmsum, out, blockmax, badflag);
    hipLaunchKernelGGL(fix_kernel, dim3(BS * QN), dim3(128), 0, stream,
                       out, blockmax, badflag);
}